// Round 8
// baseline (133.545 us; speedup 1.0000x reference)
//
#include <hip/hip_runtime.h>

typedef __bf16 bf16_t;
typedef bf16_t bf16x8 __attribute__((ext_vector_type(8)));
typedef float f32x4 __attribute__((ext_vector_type(4)));

#define NSEQ 2048
#define EMB 512
#define HEADS 8
#define HD 64
#define BATCH 4
#define LOG2E 1.4426950408889634f

#define XELEMS (BATCH * NSEQ * EMB)   // 4194304 x elements
#define WELEMS (EMB * EMB)            // 262144 per W

#define MFMA16(a, b, c) __builtin_amdgcn_mfma_f32_16x16x32_bf16(a, b, c, 0, 0, 0)

// Fragment-major layouts (frag = 64 lanes x 8 bf16, contiguous 1 KB):
//   Kf[((bh*128 + kt16)*2 + kk)*512 + lane*8 + j]
//       = K[bh][key = kt16*16 + (lane&15)][d = kk*32 + (lane>>4)*8 + j]
//   Vf[((bh*64 + kt32)*4 + dt)*512 + lane*8 + j]
//       = V[bh][key = kt32*32 + PERM(lane>>4, j)][d = dt*16 + (lane&15)]
// V key order is PERMUTED to match flash's in-register P transpose:
//   PERM(q, j) = (q>>1)*16 + (q&1)*4 + (j>>2)*8 + (j&3)

// ---------------------------------------------------------------------------
// Convert pass: x, Wk, Wv (fp32) -> bf16, written into d_out-as-scratch.
// (R11-validated; flash fully overwrites d_out afterwards, stream-ordered.)
// ---------------------------------------------------------------------------
__global__ __launch_bounds__(256) void convert_kernel(
    const float* __restrict__ x, const float* __restrict__ Wk,
    const float* __restrict__ Wv, bf16_t* __restrict__ xb)
{
  const int i = blockIdx.x * 256 + threadIdx.x;   // 8-element group id
  const float* src;
  size_t off;
  bf16_t* dst;
  if (i < XELEMS / 8) {
    off = (size_t)i * 8;
    src = x;
    dst = xb + off;
  } else {
    const size_t e = (size_t)(i - XELEMS / 8) * 8;   // 0 .. 2*WELEMS-8
    if (e < WELEMS) { src = Wk; off = e; }
    else            { src = Wv; off = e - WELEMS; }
    dst = xb + XELEMS + e;
  }
  const float4 a = *(const float4*)(src + off);
  const float4 b = *(const float4*)(src + off + 4);
  bf16x8 v;
  v[0] = (bf16_t)a.x; v[1] = (bf16_t)a.y; v[2] = (bf16_t)a.z; v[3] = (bf16_t)a.w;
  v[4] = (bf16_t)b.x; v[5] = (bf16_t)b.y; v[6] = (bf16_t)b.z; v[7] = (bf16_t)b.w;
  *(bf16x8*)dst = v;
}

// ---------------------------------------------------------------------------
// proj: pure-bf16 GEMM with minimum 2-phase pipeline (R12/R14-validated):
// double-buffered LDS (64 KB), stage(it+1) issued BEFORE consuming tile it,
// one __syncthreads per K-step. XOR-swizzle: linear LDS dest +
// inverse-swizzled global source + swizzled read. Fragment contents / acc
// layout / Kf,Vf epilogue unchanged.
// ---------------------------------------------------------------------------
__global__ __launch_bounds__(256, 2) void proj_kernel(
    const bf16_t* __restrict__ xb, const bf16_t* __restrict__ Wb,
    const float* __restrict__ bk, const float* __restrict__ bv,
    bf16_t* __restrict__ Kf, bf16_t* __restrict__ Vf)
{
  __shared__ union {
    struct {
      __align__(16) bf16_t A[2][128 * 64];  // [dbuf][row*64 + swizzled chunk]
      __align__(16) bf16_t B[2][128 * 64];
    } s;
    __align__(16) bf16_t T[128][136];       // epilogue relayout buffer
  } u;

  const int t    = threadIdx.x;
  const int w    = t >> 6;
  const int lane = t & 63;
  const int quad = lane >> 4;
  const int l15  = lane & 15;
  const int wr   = w >> 1, wc = w & 1;
  const int m0   = blockIdx.x * 128;
  const int n0   = blockIdx.y * 128;      // stacked feature base 0..896
  const int zz   = (blockIdx.y >= 4);     // 0: K-features, 1: V-features

  const int rsub = lane >> 3;
  const int cswz = (lane & 7) ^ rsub;

  auto stage = [&](int it, int bufi) {
    const int kb = it * 64;               // k element base of this tile
#pragma unroll
    for (int g = 0; g < 4; ++g) {
      const int r = w * 32 + g * 8;       // group row base (uniform per wave)
      const bf16_t* gA = xb + (size_t)(m0 + r + rsub) * EMB + kb + cswz * 8;
      const bf16_t* gB = Wb + (size_t)(n0 + r + rsub) * EMB + kb + cswz * 8;
      __builtin_amdgcn_global_load_lds(
          (const __attribute__((address_space(1))) void*)gA,
          (__attribute__((address_space(3))) void*)&u.s.A[bufi][r * 64], 16, 0, 0);
      __builtin_amdgcn_global_load_lds(
          (const __attribute__((address_space(1))) void*)gB,
          (__attribute__((address_space(3))) void*)&u.s.B[bufi][r * 64], 16, 0, 0);
    }
  };
  auto rdA = [&](int bufi, int R, int c) {
    return *(const bf16x8*)(&u.s.A[bufi][R * 64 + ((c ^ (R & 7)) << 3)]);
  };
  auto rdB = [&](int bufi, int R, int c) {
    return *(const bf16x8*)(&u.s.B[bufi][R * 64 + ((c ^ (R & 7)) << 3)]);
  };

  f32x4 acc[4][4] = {};

  stage(0, 0);
  __syncthreads();                        // tile 0 resident

  for (int it = 0; it < 8; ++it) {
    const int cur = it & 1;
    if (it < 7) stage(it + 1, cur ^ 1);   // issue next-tile DMA FIRST

    bf16x8 af[4][2], bfr[4][2];
#pragma unroll
    for (int mt = 0; mt < 4; ++mt)
#pragma unroll
      for (int kk = 0; kk < 2; ++kk)
        af[mt][kk] = rdA(cur, wr * 64 + mt * 16 + l15, kk * 4 + quad);
#pragma unroll
    for (int nt = 0; nt < 4; ++nt)
#pragma unroll
      for (int kk = 0; kk < 2; ++kk)
        bfr[nt][kk] = rdB(cur, wc * 64 + nt * 16 + l15, kk * 4 + quad);
#pragma unroll
    for (int kk = 0; kk < 2; ++kk)
#pragma unroll
      for (int mt = 0; mt < 4; ++mt)
#pragma unroll
        for (int nt = 0; nt < 4; ++nt)
          acc[mt][nt] = MFMA16(af[mt][kk], bfr[nt][kk], acc[mt][nt]);

    __syncthreads();
  }

  // Stage 1: +bias, bf16, into LDS (K: row-major [n][feat]; V: [feat][n]).
#pragma unroll
  for (int mt = 0; mt < 4; ++mt) {
#pragma unroll
    for (int nt = 0; nt < 4; ++nt) {
      const int F = wc * 64 + nt * 16 + l15;       // local feature 0..127
      const int c = n0 + F;                        // stacked feature 0..1023
      const float bb = zz ? bv[c - 512] : bk[c];
#pragma unroll
      for (int reg = 0; reg < 4; ++reg) {
        const int R = wr * 64 + mt * 16 + quad * 4 + reg;  // local row 0..127
        const float v = acc[mt][nt][reg] + bb;
        if (!zz) u.T[R][F] = (bf16_t)v;
        else     u.T[F][R] = (bf16_t)v;
      }
    }
  }
  __syncthreads();

  // Stage 2: fragment-major coalesced stores (1 KB per wave-store).
  if (!zz) {
    // 32 frags: hL(2) x kk(2) x ktl(8)
#pragma unroll
    for (int i = 0; i < 8; ++i) {
      const int fi  = i * 4 + w;
      const int hL  = fi >> 4, kk = (fi >> 3) & 1, ktl = fi & 7;
      const bf16x8 v = *(const bf16x8*)(&u.T[ktl * 16 + l15][hL * 64 + kk * 32 + quad * 8]);
      const int gr = m0 + ktl * 16 + l15;          // global key row
      const int b = gr >> 11, n = gr & (NSEQ - 1);
      const int bh = b * HEADS + (n0 >> 6) + hL;
      bf16_t* dst = Kf + (((size_t)(bh * 128 + (n >> 4)) * 2 + kk)) * 512 + lane * 8;
      *(bf16x8*)dst = v;
    }
  } else {
    // 32 frags: hL(2) x dt(4) x k32l(4); key order PERM(quad, j).
#pragma unroll
    for (int i = 0; i < 8; ++i) {
      const int fi   = i * 4 + w;
      const int hL   = fi >> 4, dt = (fi >> 2) & 3, k32l = fi & 3;
      const bf16_t* Trow = &u.T[hL * 64 + dt * 16 + l15][0];
      const int r0 = k32l * 32 + (quad >> 1) * 16 + (quad & 1) * 4;
      union { uint2 d2[2]; bf16x8 v; } vv;
      vv.d2[0] = *(const uint2*)(Trow + r0);       // keys r0..r0+3  -> j=0..3
      vv.d2[1] = *(const uint2*)(Trow + r0 + 8);   // keys r0+8..+11 -> j=4..7
      const int gr = m0 + k32l * 32;               // key base (same b for block)
      const int b = gr >> 11, n = gr & (NSEQ - 1);
      const int bh = b * HEADS + ((n0 - 512) >> 6) + hL;
      bf16_t* dst = Vf + (((size_t)(bh * 64 + (n >> 5)) * 4 + dt)) * 512 + lane * 8;
      *(bf16x8*)dst = vv.v;
    }
  }
}

// ---------------------------------------------------------------------------
// Flash attention, Q = K, fixed max m_i = ||k_i||^2, S^T trick.
// R15: SHRINK THE WAVE TILE to fit 3 waves/SIMD — the inverse of R13.
// R9's wave (4 row-tiles) demands ~184 unified regs -> hard 2 waves/SIMD;
// every cap below demand spilled (R12: cap 128, R13: cap 170). Here each
// wave owns 2 ROW-TILES (32 q-rows): qf 32->16, st 32->16, pf 16->8,
// acco 64->32 AGPR, accll 16->8 AGPR. Static demand ~130 << 170 cap of
// __launch_bounds__(256,3) -> 3 waves/SIMD with a 40-reg margin.
// Block = 64 rows (2 rh) x 2 kh key-halves; grid (32, 32) = 1024 blocks =
// 4/CU, 3 co-resident. Chip-wide work unchanged; K-load L2 traffic doubles
// (L2-resident; all row-blocks of one bh land on one XCD: id%8 = bh%8).
// Body is R9's verbatim with nt/rt ranges halved. LDS 20.5 KB.
// Spill tripwire: WRITE_SIZE must stay 16384 KB.
// ---------------------------------------------------------------------------
__global__ __launch_bounds__(256, 3) void flash_kernel(
    const bf16_t* __restrict__ Kf, const bf16_t* __restrict__ Vf,
    float* __restrict__ out)
{
  __shared__ struct {
    __align__(16) float Cb[2][2048];       // [rh] key-half-1 O partials (16 KB)
    __align__(16) float Lb[2][64][8];      // [rh] key-half-1 l partials (4 KB)
  } u;

  const int t    = threadIdx.x;
  const int w    = t >> 6;
  const int lane = t & 63;
  const int quad = lane >> 4;
  const int l15  = lane & 15;
  const int rh   = w & 1;              // row-half (32 rows each)
  const int kh   = w >> 1;             // key-half

  const int bh = blockIdx.x;           // 0..31 (id%8 = bh%8 -> XCD locality)
  const int b  = bh >> 3, h = bh & 7;
  const int rowbase = blockIdx.y * 64 + rh * 32;
  const int qtile   = rowbase >> 4;    // 16-row tile base 0..126

  const bf16_t* __restrict__ Kb = Kf + (size_t)bh * 128 * 2 * 512;
  const bf16_t* __restrict__ Vb = Vf + (size_t)bh * 64 * 4 * 512;

  // Resident Q fragments (coalesced frag loads; B-operand of S^T).
  bf16x8 qf[2][2];
#pragma unroll
  for (int nt = 0; nt < 2; ++nt)
#pragma unroll
    for (int kk = 0; kk < 2; ++kk)
      qf[nt][kk] = *(const bf16x8*)(Kb + ((size_t)(qtile + nt) * 2 + kk) * 512 + lane * 8);

  // Fixed max m_i = ||k_i||^2; lane's q-row for tile nt is nt*16+l15.
  float mlog[2];
#pragma unroll
  for (int nt = 0; nt < 2; ++nt) {
    float ss = 0.f;
#pragma unroll
    for (int kk = 0; kk < 2; ++kk)
#pragma unroll
      for (int j = 0; j < 8; ++j) {
        const float qv = (float)qf[nt][kk][j];
        ss = fmaf(qv, qv, ss);
      }
    ss += __shfl_xor(ss, 16, 64);
    ss += __shfl_xor(ss, 32, 64);
    mlog[nt] = ss * LOG2E;
  }

  bf16x8 ones;
#pragma unroll
  for (int j = 0; j < 8; ++j) ones[j] = (bf16_t)1.0f;

  f32x4 acco[2][4] = {};   // [row-tile][d-tile]
  f32x4 accll[2]   = {};   // l partials via ones-MFMA (C-layout)

  // K frag loader: keys kt*64 + kh*32 .. +31 = 16-key tiles kt*4+kh*2+{0,1}
  auto load_k = [&](int kt, bf16x8 (&dst)[2][2]) {
    const int kb = kt * 4 + kh * 2;
#pragma unroll
    for (int jt = 0; jt < 2; ++jt)
#pragma unroll
      for (int kk = 0; kk < 2; ++kk)
        dst[jt][kk] =
            *(const bf16x8*)(Kb + ((size_t)(kb + jt) * 2 + kk) * 512 + lane * 8);
  };

  // One tile: uses kcur (resident), prefetches kt+1 into knxt.
  auto body = [&](int kt, bf16x8 (&kcur)[2][2], bf16x8 (&knxt)[2][2]) {
    // V frags for current tile (consumed after S-phase).
    bf16x8 vf[4];
    const int v32 = kt * 2 + kh;
#pragma unroll
    for (int dt = 0; dt < 4; ++dt)
      vf[dt] = *(const bf16x8*)(Vb + ((size_t)v32 * 4 + dt) * 512 + lane * 8);

    // S^T = K . Q^T.
    f32x4 st[2][2] = {};
    __builtin_amdgcn_s_setprio(1);
#pragma unroll
    for (int kk = 0; kk < 2; ++kk)
#pragma unroll
      for (int jt = 0; jt < 2; ++jt)
#pragma unroll
        for (int nt = 0; nt < 2; ++nt)
          st[jt][nt] = MFMA16(kcur[jt][kk], qf[nt][kk], st[jt][nt]);
    __builtin_amdgcn_s_setprio(0);

    // Prefetch next K tile (clamped on last iter).
    load_k(kt + 1 < NSEQ / 64 ? kt + 1 : kt, knxt);

    // P = exp2(S*log2e - m), packed to bf16 pairs and transposed C->A
    // in-register: two permlane32_swap per row-tile. Resulting lane key
    // order is PERM(quad, j), which Vf's store order matches.
    bf16x8 pf[2];
#pragma unroll
    for (int nt = 0; nt < 2; ++nt) {
      union { bf16_t h[2]; unsigned uu; } w00, w01, w10, w11;
      w00.h[0] = (bf16_t)__builtin_amdgcn_exp2f(fmaf(st[0][nt][0], LOG2E, -mlog[nt]));
      w00.h[1] = (bf16_t)__builtin_amdgcn_exp2f(fmaf(st[0][nt][1], LOG2E, -mlog[nt]));
      w01.h[0] = (bf16_t)__builtin_amdgcn_exp2f(fmaf(st[0][nt][2], LOG2E, -mlog[nt]));
      w01.h[1] = (bf16_t)__builtin_amdgcn_exp2f(fmaf(st[0][nt][3], LOG2E, -mlog[nt]));
      w10.h[0] = (bf16_t)__builtin_amdgcn_exp2f(fmaf(st[1][nt][0], LOG2E, -mlog[nt]));
      w10.h[1] = (bf16_t)__builtin_amdgcn_exp2f(fmaf(st[1][nt][1], LOG2E, -mlog[nt]));
      w11.h[0] = (bf16_t)__builtin_amdgcn_exp2f(fmaf(st[1][nt][2], LOG2E, -mlog[nt]));
      w11.h[1] = (bf16_t)__builtin_amdgcn_exp2f(fmaf(st[1][nt][3], LOG2E, -mlog[nt]));
      // swap row1(a)<->row0(b): a' = quads {a.q0, a.q1, b.q0, b.q1},
      //                         b' = quads {a.q2, a.q3, b.q2, b.q3}
      auto r0 = __builtin_amdgcn_permlane32_swap(w00.uu, w10.uu, false, false);
      auto r1 = __builtin_amdgcn_permlane32_swap(w01.uu, w11.uu, false, false);
      union { unsigned uw[4]; bf16x8 v; } pk;
      pk.uw[0] = r0[0]; pk.uw[1] = r1[0]; pk.uw[2] = r0[1]; pk.uw[3] = r1[1];
      pf[nt] = pk.v;
    }

    // O += P V, l += P . 1 (all in registers).
    __builtin_amdgcn_s_setprio(1);
#pragma unroll
    for (int rt = 0; rt < 2; ++rt) {
      accll[rt] = MFMA16(pf[rt], ones, accll[rt]);
#pragma unroll
      for (int dt = 0; dt < 4; ++dt)
        acco[rt][dt] = MFMA16(pf[rt], vf[dt], acco[rt][dt]);
    }
    __builtin_amdgcn_s_setprio(0);
  };

  bf16x8 kA[2][2], kB[2][2];
  load_k(0, kA);
  for (int kt = 0; kt < NSEQ / 64; kt += 2) {
    body(kt,     kA, kB);   // static buffer names -> no dynamic reg indexing
    body(kt + 1, kB, kA);
  }

  // Split-K combine: key-half-1 waves dump partials; key-half-0 waves add.
  __syncthreads();
  if (kh == 1) {
#pragma unroll
    for (int rt = 0; rt < 2; ++rt) {
#pragma unroll
      for (int dt = 0; dt < 4; ++dt)
        *(f32x4*)(&u.Cb[rh][((rt * 4 + dt) * 64 + lane) * 4]) = acco[rt][dt];
      *(f32x4*)(&u.Lb[rh][lane][rt * 4]) = accll[rt];
    }
  }
  __syncthreads();
  if (kh == 0) {
#pragma unroll
    for (int rt = 0; rt < 2; ++rt) {
#pragma unroll
      for (int dt = 0; dt < 4; ++dt)
        acco[rt][dt] += *(const f32x4*)(&u.Cb[rh][((rt * 4 + dt) * 64 + lane) * 4]);
      accll[rt] += *(const f32x4*)(&u.Lb[rh][lane][rt * 4]);
    }

    const float SCL = 0.044194173824159216f;  // 1/sqrt(512)
    // accll[rt][reg] = l of q-row rt*16+quad*4+reg — already acco-aligned.
#pragma unroll
    for (int rt = 0; rt < 2; ++rt)
#pragma unroll
      for (int reg = 0; reg < 4; ++reg) {
        const float f = SCL / accll[rt][reg];
        const int n = rowbase + rt * 16 + quad * 4 + reg;
#pragma unroll
        for (int dt = 0; dt < 4; ++dt)
          out[((size_t)(b * NSEQ + n)) * EMB + h * HD + dt * 16 + l15] =
              acco[rt][dt][reg] * f;
      }
  }
}

extern "C" void kernel_launch(void* const* d_in, const int* in_sizes, int n_in,
                              void* d_out, int out_size, void* d_ws, size_t ws_size,
                              hipStream_t stream) {
  const float* x  = (const float*)d_in[0];
  const float* Wk = (const float*)d_in[1];
  const float* bk = (const float*)d_in[2];
  const float* Wv = (const float*)d_in[3];
  const float* bv = (const float*)d_in[4];
  float* out = (float*)d_out;

  bf16_t* Kf = (bf16_t*)d_ws;                                   // 8 MB
  bf16_t* Vf = Kf + (size_t)BATCH * HEADS * NSEQ * HD;          // 8 MB

  // d_out doubles as convert scratch (9.4 MB of 16.8 MB); flash fully
  // overwrites it afterwards, stream-ordered.
  bf16_t* xb = (bf16_t*)d_out;            // [8192][512] bf16
  bf16_t* Wb = xb + XELEMS;               // [1024][512] bf16 stacked Wk;Wv

  convert_kernel<<<(XELEMS / 8 + 2 * WELEMS / 8) / 256, 256, 0, stream>>>(
      x, Wk, Wv, xb);

  dim3 pg(8192 / 128, 1024 / 128);
  proj_kernel<<<pg, 256, 0, stream>>>(xb, Wb, bk, bv, Kf, Vf);

  dim3 fg(BATCH * HEADS, NSEQ / 64);
  flash_kernel<<<fg, 256, 0, stream>>>(Kf, Vf, out);
}

// Round 9
// 130.958 us; speedup vs baseline: 1.0198x; 1.0198x over previous
//
#include <hip/hip_runtime.h>

typedef __bf16 bf16_t;
typedef bf16_t bf16x8 __attribute__((ext_vector_type(8)));
typedef float f32x4 __attribute__((ext_vector_type(4)));

#define NSEQ 2048
#define EMB 512
#define HEADS 8
#define HD 64
#define BATCH 4
#define LOG2E 1.4426950408889634f

#define MFMA16(a, b, c) __builtin_amdgcn_mfma_f32_16x16x32_bf16(a, b, c, 0, 0, 0)

// Fragment-major layouts (frag = 64 lanes x 8 bf16, contiguous 1 KB):
//   Kf[((bh*128 + kt16)*2 + kk)*512 + lane*8 + j]
//       = K[bh][key = kt16*16 + (lane&15)][d = kk*32 + (lane>>4)*8 + j]
//   Vf[((bh*64 + kt32)*4 + dt)*512 + lane*8 + j]
//       = V[bh][key = kt32*32 + PERM(lane>>4, j)][d = dt*16 + (lane&15)]
// V key order is PERMUTED to match flash's in-register P transpose:
//   PERM(q, j) = (q>>1)*16 + (q&1)*4 + (j>>2)*8 + (j&3)

// ---------------------------------------------------------------------------
// Fused K/V projection GEMM with inline fp32->bf16 convert (R1-validated,
// ~35us; the convert+bf16-GEMM split measured NET WORSE by ~2us, reverted):
// C[8192,1024] = x @ [Wk;Wv]^T + [bk;bv]. 128x128 tile, BK=64,
// register-prefetch pipeline. Epilogue emits FRAGMENT-MAJOR Kf/Vf.
// ---------------------------------------------------------------------------
__global__ __launch_bounds__(256, 2) void proj_kernel(
    const float* __restrict__ x,
    const float* __restrict__ Wk, const float* __restrict__ bk,
    const float* __restrict__ Wv, const float* __restrict__ bv,
    bf16_t* __restrict__ Kf, bf16_t* __restrict__ Vf)
{
  __shared__ union {
    struct {
      __align__(16) bf16_t A[2][128][40];   // [kk-half][row][32 el + pad]
      __align__(16) bf16_t B[2][128][40];
    } s;
    __align__(16) bf16_t T[128][136];       // epilogue relayout buffer
  } u;

  const int t    = threadIdx.x;
  const int w    = t >> 6;
  const int lane = t & 63;
  const int quad = lane >> 4;
  const int l15  = lane & 15;
  const int wr   = w >> 1, wc = w & 1;
  const int m0   = blockIdx.x * 128;
  const int n0   = blockIdx.y * 128;        // stacked feature base 0..896
  const int zz   = (blockIdx.y >= 4);       // 0: K-features, 1: V-features
  const float* __restrict__ W = zz ? Wv : Wk;
  const int nW = n0 - zz * 512;             // row base within W

  const int sr = t >> 3;        // staging row 0..31 (x4 groups)
  const int sj = t & 7;         // 8-el chunk 0..7 within 64-el k slab
  const int sb = sj >> 2, sc = (sj & 3) * 8;

  float4 pa[4][2], pb[4][2];
  auto prefetch = [&](int k0) {
#pragma unroll
    for (int i = 0; i < 4; ++i) {
      const float* xa = x + (size_t)(m0 + sr + i * 32) * EMB + k0 + sj * 8;
      const float* wa = W + (size_t)(nW + sr + i * 32) * EMB + k0 + sj * 8;
      pa[i][0] = *(const float4*)xa; pa[i][1] = *(const float4*)(xa + 4);
      pb[i][0] = *(const float4*)wa; pb[i][1] = *(const float4*)(wa + 4);
    }
  };
  auto pack8 = [](float4 a, float4 b) -> bf16x8 {
    bf16x8 v;
    v[0] = (bf16_t)a.x; v[1] = (bf16_t)a.y; v[2] = (bf16_t)a.z; v[3] = (bf16_t)a.w;
    v[4] = (bf16_t)b.x; v[5] = (bf16_t)b.y; v[6] = (bf16_t)b.z; v[7] = (bf16_t)b.w;
    return v;
  };

  f32x4 acc[4][4] = {};
  prefetch(0);

  for (int it = 0; it < 8; ++it) {
    __syncthreads();
#pragma unroll
    for (int i = 0; i < 4; ++i) {
      *(bf16x8*)(&u.s.A[sb][sr + i * 32][sc]) = pack8(pa[i][0], pa[i][1]);
      *(bf16x8*)(&u.s.B[sb][sr + i * 32][sc]) = pack8(pb[i][0], pb[i][1]);
    }
    __syncthreads();
    if (it < 7) prefetch((it + 1) * 64);

    bf16x8 af[4][2], bf[4][2];
#pragma unroll
    for (int mt = 0; mt < 4; ++mt)
#pragma unroll
      for (int kk = 0; kk < 2; ++kk)
        af[mt][kk] = *(const bf16x8*)(&u.s.A[kk][wr * 64 + mt * 16 + l15][quad * 8]);
#pragma unroll
    for (int nt = 0; nt < 4; ++nt)
#pragma unroll
      for (int kk = 0; kk < 2; ++kk)
        bf[nt][kk] = *(const bf16x8*)(&u.s.B[kk][wc * 64 + nt * 16 + l15][quad * 8]);
#pragma unroll
    for (int kk = 0; kk < 2; ++kk)
#pragma unroll
      for (int mt = 0; mt < 4; ++mt)
#pragma unroll
        for (int nt = 0; nt < 4; ++nt)
          acc[mt][nt] = MFMA16(af[mt][kk], bf[nt][kk], acc[mt][nt]);
  }

  __syncthreads();  // staging LDS -> relayout buffer reuse

  // Stage 1: +bias, bf16, into LDS (K: row-major [n][feat]; V: [feat][n]).
#pragma unroll
  for (int mt = 0; mt < 4; ++mt) {
#pragma unroll
    for (int nt = 0; nt < 4; ++nt) {
      const int F = wc * 64 + nt * 16 + l15;       // local feature 0..127
      const int c = n0 + F;                        // stacked feature 0..1023
      const float bb = zz ? bv[c - 512] : bk[c];
#pragma unroll
      for (int reg = 0; reg < 4; ++reg) {
        const int R = wr * 64 + mt * 16 + quad * 4 + reg;  // local row 0..127
        const float v = acc[mt][nt][reg] + bb;
        if (!zz) u.T[R][F] = (bf16_t)v;
        else     u.T[F][R] = (bf16_t)v;
      }
    }
  }
  __syncthreads();

  // Stage 2: fragment-major coalesced stores (1 KB per wave-store).
  if (!zz) {
    // 32 frags: hL(2) x kk(2) x ktl(8)
#pragma unroll
    for (int i = 0; i < 8; ++i) {
      const int fi  = i * 4 + w;
      const int hL  = fi >> 4, kk = (fi >> 3) & 1, ktl = fi & 7;
      const bf16x8 v = *(const bf16x8*)(&u.T[ktl * 16 + l15][hL * 64 + kk * 32 + quad * 8]);
      const int gr = m0 + ktl * 16 + l15;          // global key row
      const int b = gr >> 11, n = gr & (NSEQ - 1);
      const int bh = b * HEADS + (n0 >> 6) + hL;
      bf16_t* dst = Kf + (((size_t)(bh * 128 + (n >> 4)) * 2 + kk)) * 512 + lane * 8;
      *(bf16x8*)dst = v;
    }
  } else {
    // 32 frags: hL(2) x dt(4) x k32l(4); key order PERM(quad, j).
#pragma unroll
    for (int i = 0; i < 8; ++i) {
      const int fi   = i * 4 + w;
      const int hL   = fi >> 4, dt = (fi >> 2) & 3, k32l = fi & 3;
      const bf16_t* Trow = &u.T[hL * 64 + dt * 16 + l15][0];
      const int r0 = k32l * 32 + (quad >> 1) * 16 + (quad & 1) * 4;
      union { uint2 d2[2]; bf16x8 v; } vv;
      vv.d2[0] = *(const uint2*)(Trow + r0);       // keys r0..r0+3  -> j=0..3
      vv.d2[1] = *(const uint2*)(Trow + r0 + 8);   // keys r0+8..+11 -> j=4..7
      const int gr = m0 + k32l * 32;               // key base (same b for block)
      const int b = gr >> 11, n = gr & (NSEQ - 1);
      const int bh = b * HEADS + ((n0 - 512) >> 6) + hL;
      bf16_t* dst = Vf + (((size_t)(bh * 64 + (n >> 5)) * 4 + dt)) * 512 + lane * 8;
      *(bf16x8*)dst = vv.v;
    }
  }
}

// ---------------------------------------------------------------------------
// Flash attention, Q = K, fixed max m_i = ||k_i||^2, S^T trick.
// R16 = R9 minus the ones-MFMA l-accumulation. R15 proved the kernel is
// ISSUE-THROUGHPUT-bound, not occupancy-bound (+76% waves -> +-0% time), so
// the only lever is removing issued work: the l row-sum was 4 of 36 MFMAs
// per body (11% of MFMA-busy); replaced by 8 f32 adds in C-layout per body
// (R10/R13-validated l-path), one shuffle-reduce + 2KB LDS transpose after
// the loop. Register demand strictly decreases (-16 AGPR, -4 VGPR) at the
// proven 2-waves/SIMD operating point — spill tripwire cannot fire.
// In-register P relayout: S^T C-layout -> A-layout via bf16 pair-packing +
// 2x permlane32_swap; Vf's PERM key order absorbs the lane permutation.
// ---------------------------------------------------------------------------
__global__ __launch_bounds__(256, 2) void flash_kernel(
    const bf16_t* __restrict__ Kf, const bf16_t* __restrict__ Vf,
    float* __restrict__ out)
{
  __shared__ struct {
    __align__(16) float Cb[2][4096];       // key-half-1 O partials (32 KB)
    __align__(16) float Lb[2][2][64];      // [kh][rh][row] l partials (2 KB)
  } u;

  const int t    = threadIdx.x;
  const int w    = t >> 6;
  const int lane = t & 63;
  const int quad = lane >> 4;
  const int l15  = lane & 15;
  const int rh   = w & 1;              // row-half
  const int kh   = w >> 1;             // key-half

  const int bh = blockIdx.x;           // 0..31 (id%8 = bh%8 -> XCD locality)
  const int b  = bh >> 3, h = bh & 7;
  const int rowbase = blockIdx.y * 128 + rh * 64;
  const int qtile   = rowbase >> 4;    // 16-row tile base 0..124

  const bf16_t* __restrict__ Kb = Kf + (size_t)bh * 128 * 2 * 512;
  const bf16_t* __restrict__ Vb = Vf + (size_t)bh * 64 * 4 * 512;

  // Resident Q fragments (coalesced frag loads; B-operand of S^T).
  bf16x8 qf[4][2];
#pragma unroll
  for (int nt = 0; nt < 4; ++nt)
#pragma unroll
    for (int kk = 0; kk < 2; ++kk)
      qf[nt][kk] = *(const bf16x8*)(Kb + ((size_t)(qtile + nt) * 2 + kk) * 512 + lane * 8);

  // Fixed max m_i = ||k_i||^2; lane's q-row for tile nt is nt*16+l15.
  float mlog[4];
#pragma unroll
  for (int nt = 0; nt < 4; ++nt) {
    float ss = 0.f;
#pragma unroll
    for (int kk = 0; kk < 2; ++kk)
#pragma unroll
      for (int j = 0; j < 8; ++j) {
        const float qv = (float)qf[nt][kk][j];
        ss = fmaf(qv, qv, ss);
      }
    ss += __shfl_xor(ss, 16, 64);
    ss += __shfl_xor(ss, 32, 64);
    mlog[nt] = ss * LOG2E;
  }

  f32x4 acco[4][4] = {};                  // [row-tile][d-tile]
  float lsum[4] = {0.f, 0.f, 0.f, 0.f};   // l partial, C-layout (row = l15)

  // K frag loader: keys kt*64 + kh*32 .. +31 = 16-key tiles kt*4+kh*2+{0,1}
  auto load_k = [&](int kt, bf16x8 (&dst)[2][2]) {
    const int kb = kt * 4 + kh * 2;
#pragma unroll
    for (int jt = 0; jt < 2; ++jt)
#pragma unroll
      for (int kk = 0; kk < 2; ++kk)
        dst[jt][kk] =
            *(const bf16x8*)(Kb + ((size_t)(kb + jt) * 2 + kk) * 512 + lane * 8);
  };

  // One tile: uses kcur (resident), prefetches kt+1 into knxt.
  auto body = [&](int kt, bf16x8 (&kcur)[2][2], bf16x8 (&knxt)[2][2]) {
    // V frags for current tile (consumed after S-phase).
    bf16x8 vf[4];
    const int v32 = kt * 2 + kh;
#pragma unroll
    for (int dt = 0; dt < 4; ++dt)
      vf[dt] = *(const bf16x8*)(Vb + ((size_t)v32 * 4 + dt) * 512 + lane * 8);

    // S^T = K . Q^T.
    f32x4 st[2][4] = {};
    __builtin_amdgcn_s_setprio(1);
#pragma unroll
    for (int kk = 0; kk < 2; ++kk)
#pragma unroll
      for (int jt = 0; jt < 2; ++jt)
#pragma unroll
        for (int nt = 0; nt < 4; ++nt)
          st[jt][nt] = MFMA16(kcur[jt][kk], qf[nt][kk], st[jt][nt]);
    __builtin_amdgcn_s_setprio(0);

    // Prefetch next K tile (clamped on last iter).
    load_k(kt + 1 < NSEQ / 64 ? kt + 1 : kt, knxt);

    // P = exp2(S*log2e - m); f32 l-sum in C-layout; pack to bf16 pairs and
    // transpose C->A via 2x permlane32_swap (key order PERM, matched by Vf).
    bf16x8 pf[4];
#pragma unroll
    for (int nt = 0; nt < 4; ++nt) {
      const float m = mlog[nt];
      const float e0 = __builtin_amdgcn_exp2f(fmaf(st[0][nt][0], LOG2E, -m));
      const float e1 = __builtin_amdgcn_exp2f(fmaf(st[0][nt][1], LOG2E, -m));
      const float e2 = __builtin_amdgcn_exp2f(fmaf(st[0][nt][2], LOG2E, -m));
      const float e3 = __builtin_amdgcn_exp2f(fmaf(st[0][nt][3], LOG2E, -m));
      const float e4 = __builtin_amdgcn_exp2f(fmaf(st[1][nt][0], LOG2E, -m));
      const float e5 = __builtin_amdgcn_exp2f(fmaf(st[1][nt][1], LOG2E, -m));
      const float e6 = __builtin_amdgcn_exp2f(fmaf(st[1][nt][2], LOG2E, -m));
      const float e7 = __builtin_amdgcn_exp2f(fmaf(st[1][nt][3], LOG2E, -m));
      lsum[nt] += ((e0 + e1) + (e2 + e3)) + ((e4 + e5) + (e6 + e7));

      union { bf16_t hx[2]; unsigned uu; } w00, w01, w10, w11;
      w00.hx[0] = (bf16_t)e0; w00.hx[1] = (bf16_t)e1;
      w01.hx[0] = (bf16_t)e2; w01.hx[1] = (bf16_t)e3;
      w10.hx[0] = (bf16_t)e4; w10.hx[1] = (bf16_t)e5;
      w11.hx[0] = (bf16_t)e6; w11.hx[1] = (bf16_t)e7;
      // swap row1(a)<->row0(b): a' = quads {a.q0, a.q1, b.q0, b.q1},
      //                         b' = quads {a.q2, a.q3, b.q2, b.q3}
      auto r0 = __builtin_amdgcn_permlane32_swap(w00.uu, w10.uu, false, false);
      auto r1 = __builtin_amdgcn_permlane32_swap(w01.uu, w11.uu, false, false);
      union { unsigned uw[4]; bf16x8 v; } pk;
      pk.uw[0] = r0[0]; pk.uw[1] = r1[0]; pk.uw[2] = r0[1]; pk.uw[3] = r1[1];
      pf[nt] = pk.v;
    }

    // O += P V (all in registers).
    __builtin_amdgcn_s_setprio(1);
#pragma unroll
    for (int rt = 0; rt < 4; ++rt)
#pragma unroll
      for (int dt = 0; dt < 4; ++dt)
        acco[rt][dt] = MFMA16(pf[rt], vf[dt], acco[rt][dt]);
    __builtin_amdgcn_s_setprio(0);
  };

  bf16x8 kA[2][2], kB[2][2];
  load_k(0, kA);
  for (int kt = 0; kt < NSEQ / 64; kt += 2) {
    body(kt,     kA, kB);   // static buffer names -> no dynamic reg indexing
    body(kt + 1, kB, kA);
  }

  // l: reduce across quads (C-layout row = l15), stage through LDS to reach
  // the acco-aligned layout (row = quad*4+reg) and combine kh halves.
#pragma unroll
  for (int nt = 0; nt < 4; ++nt) {
    lsum[nt] += __shfl_xor(lsum[nt], 16, 64);
    lsum[nt] += __shfl_xor(lsum[nt], 32, 64);
    u.Lb[kh][rh][nt * 16 + l15] = lsum[nt];   // 4 quads dup-write same value
  }

  // Split-K combine: key-half-1 waves dump O partials; key-half-0 waves add.
  // Single barrier: all Lb/Cb writes above it, all reads below (R13-validated).
  if (kh == 1) {
#pragma unroll
    for (int rt = 0; rt < 4; ++rt)
#pragma unroll
      for (int dt = 0; dt < 4; ++dt)
        *(f32x4*)(&u.Cb[rh][((rt * 4 + dt) * 64 + lane) * 4]) = acco[rt][dt];
  }
  __syncthreads();
  if (kh == 0) {
#pragma unroll
    for (int rt = 0; rt < 4; ++rt)
#pragma unroll
      for (int dt = 0; dt < 4; ++dt)
        acco[rt][dt] += *(const f32x4*)(&u.Cb[rh][((rt * 4 + dt) * 64 + lane) * 4]);

    const float SCL = 0.044194173824159216f;  // 1/sqrt(512)
#pragma unroll
    for (int rt = 0; rt < 4; ++rt)
#pragma unroll
      for (int reg = 0; reg < 4; ++reg) {
        const int r = rt * 16 + quad * 4 + reg;
        const float l = u.Lb[0][rh][r] + u.Lb[1][rh][r];
        const float f = SCL / l;
        const int n = rowbase + r;
#pragma unroll
        for (int dt = 0; dt < 4; ++dt)
          out[((size_t)(b * NSEQ + n)) * EMB + h * HD + dt * 16 + l15] =
              acco[rt][dt][reg] * f;
      }
  }
}

extern "C" void kernel_launch(void* const* d_in, const int* in_sizes, int n_in,
                              void* d_out, int out_size, void* d_ws, size_t ws_size,
                              hipStream_t stream) {
  const float* x  = (const float*)d_in[0];
  const float* Wk = (const float*)d_in[1];
  const float* bk = (const float*)d_in[2];
  const float* Wv = (const float*)d_in[3];
  const float* bv = (const float*)d_in[4];
  float* out = (float*)d_out;

  bf16_t* Kf = (bf16_t*)d_ws;                                   // 8 MB
  bf16_t* Vf = Kf + (size_t)BATCH * HEADS * NSEQ * HD;          // 8 MB

  dim3 pg(8192 / 128, 1024 / 128);
  proj_kernel<<<pg, 256, 0, stream>>>(x, Wk, bk, Wv, bv, Kf, Vf);

  dim3 fg(BATCH * HEADS, NSEQ / 128);
  flash_kernel<<<fg, 256, 0, stream>>>(Kf, Vf, out);
}

// Round 10
// 128.839 us; speedup vs baseline: 1.0365x; 1.0164x over previous
//
#include <hip/hip_runtime.h>

typedef __bf16 bf16_t;
typedef bf16_t bf16x8 __attribute__((ext_vector_type(8)));
typedef float f32x4 __attribute__((ext_vector_type(4)));

#define NSEQ 2048
#define EMB 512
#define HEADS 8
#define HD 64
#define BATCH 4
#define LOG2E 1.4426950408889634f

#define MFMA16(a, b, c) __builtin_amdgcn_mfma_f32_16x16x32_bf16(a, b, c, 0, 0, 0)

// Fragment-major layouts (frag = 64 lanes x 8 bf16, contiguous 1 KB):
//   Kf[((bh*128 + kt16)*2 + kk)*512 + lane*8 + j]
//       = K[bh][key = kt16*16 + (lane&15)][d = kk*32 + (lane>>4)*8 + j]
//   Vf[((bh*64 + kt32)*4 + dt)*512 + lane*8 + j]
//       = V[bh][key = kt32*32 + PERM(lane>>4, j)][d = dt*16 + (lane&15)]
// V key order is PERMUTED to match flash's in-register P transpose:
//   PERM(q, j) = (q>>1)*16 + (q&1)*4 + (j>>2)*8 + (j&3)

// ---------------------------------------------------------------------------
// Fused K/V projection GEMM with inline fp32->bf16 convert (R1-validated,
// ~36us; both split-convert variants measured net worse):
// C[8192,1024] = x @ [Wk;Wv]^T + [bk;bv]. 128x128 tile, BK=64,
// register-prefetch pipeline. Epilogue emits FRAGMENT-MAJOR Kf/Vf.
// ---------------------------------------------------------------------------
__global__ __launch_bounds__(256, 2) void proj_kernel(
    const float* __restrict__ x,
    const float* __restrict__ Wk, const float* __restrict__ bk,
    const float* __restrict__ Wv, const float* __restrict__ bv,
    bf16_t* __restrict__ Kf, bf16_t* __restrict__ Vf)
{
  __shared__ union {
    struct {
      __align__(16) bf16_t A[2][128][40];   // [kk-half][row][32 el + pad]
      __align__(16) bf16_t B[2][128][40];
    } s;
    __align__(16) bf16_t T[128][136];       // epilogue relayout buffer
  } u;

  const int t    = threadIdx.x;
  const int w    = t >> 6;
  const int lane = t & 63;
  const int quad = lane >> 4;
  const int l15  = lane & 15;
  const int wr   = w >> 1, wc = w & 1;
  const int m0   = blockIdx.x * 128;
  const int n0   = blockIdx.y * 128;        // stacked feature base 0..896
  const int zz   = (blockIdx.y >= 4);       // 0: K-features, 1: V-features
  const float* __restrict__ W = zz ? Wv : Wk;
  const int nW = n0 - zz * 512;             // row base within W

  const int sr = t >> 3;        // staging row 0..31 (x4 groups)
  const int sj = t & 7;         // 8-el chunk 0..7 within 64-el k slab
  const int sb = sj >> 2, sc = (sj & 3) * 8;

  float4 pa[4][2], pb[4][2];
  auto prefetch = [&](int k0) {
#pragma unroll
    for (int i = 0; i < 4; ++i) {
      const float* xa = x + (size_t)(m0 + sr + i * 32) * EMB + k0 + sj * 8;
      const float* wa = W + (size_t)(nW + sr + i * 32) * EMB + k0 + sj * 8;
      pa[i][0] = *(const float4*)xa; pa[i][1] = *(const float4*)(xa + 4);
      pb[i][0] = *(const float4*)wa; pb[i][1] = *(const float4*)(wa + 4);
    }
  };
  auto pack8 = [](float4 a, float4 b) -> bf16x8 {
    bf16x8 v;
    v[0] = (bf16_t)a.x; v[1] = (bf16_t)a.y; v[2] = (bf16_t)a.z; v[3] = (bf16_t)a.w;
    v[4] = (bf16_t)b.x; v[5] = (bf16_t)b.y; v[6] = (bf16_t)b.z; v[7] = (bf16_t)b.w;
    return v;
  };

  f32x4 acc[4][4] = {};
  prefetch(0);

  for (int it = 0; it < 8; ++it) {
    __syncthreads();
#pragma unroll
    for (int i = 0; i < 4; ++i) {
      *(bf16x8*)(&u.s.A[sb][sr + i * 32][sc]) = pack8(pa[i][0], pa[i][1]);
      *(bf16x8*)(&u.s.B[sb][sr + i * 32][sc]) = pack8(pb[i][0], pb[i][1]);
    }
    __syncthreads();
    if (it < 7) prefetch((it + 1) * 64);

    bf16x8 af[4][2], bf[4][2];
#pragma unroll
    for (int mt = 0; mt < 4; ++mt)
#pragma unroll
      for (int kk = 0; kk < 2; ++kk)
        af[mt][kk] = *(const bf16x8*)(&u.s.A[kk][wr * 64 + mt * 16 + l15][quad * 8]);
#pragma unroll
    for (int nt = 0; nt < 4; ++nt)
#pragma unroll
      for (int kk = 0; kk < 2; ++kk)
        bf[nt][kk] = *(const bf16x8*)(&u.s.B[kk][wc * 64 + nt * 16 + l15][quad * 8]);
#pragma unroll
    for (int kk = 0; kk < 2; ++kk)
#pragma unroll
      for (int mt = 0; mt < 4; ++mt)
#pragma unroll
        for (int nt = 0; nt < 4; ++nt)
          acc[mt][nt] = MFMA16(af[mt][kk], bf[nt][kk], acc[mt][nt]);
  }

  __syncthreads();  // staging LDS -> relayout buffer reuse

  // Stage 1: +bias, bf16, into LDS (K: row-major [n][feat]; V: [feat][n]).
#pragma unroll
  for (int mt = 0; mt < 4; ++mt) {
#pragma unroll
    for (int nt = 0; nt < 4; ++nt) {
      const int F = wc * 64 + nt * 16 + l15;       // local feature 0..127
      const int c = n0 + F;                        // stacked feature 0..1023
      const float bb = zz ? bv[c - 512] : bk[c];
#pragma unroll
      for (int reg = 0; reg < 4; ++reg) {
        const int R = wr * 64 + mt * 16 + quad * 4 + reg;  // local row 0..127
        const float v = acc[mt][nt][reg] + bb;
        if (!zz) u.T[R][F] = (bf16_t)v;
        else     u.T[F][R] = (bf16_t)v;
      }
    }
  }
  __syncthreads();

  // Stage 2: fragment-major coalesced stores (1 KB per wave-store).
  if (!zz) {
    // 32 frags: hL(2) x kk(2) x ktl(8)
#pragma unroll
    for (int i = 0; i < 8; ++i) {
      const int fi  = i * 4 + w;
      const int hL  = fi >> 4, kk = (fi >> 3) & 1, ktl = fi & 7;
      const bf16x8 v = *(const bf16x8*)(&u.T[ktl * 16 + l15][hL * 64 + kk * 32 + quad * 8]);
      const int gr = m0 + ktl * 16 + l15;          // global key row
      const int b = gr >> 11, n = gr & (NSEQ - 1);
      const int bh = b * HEADS + (n0 >> 6) + hL;
      bf16_t* dst = Kf + (((size_t)(bh * 128 + (n >> 4)) * 2 + kk)) * 512 + lane * 8;
      *(bf16x8*)dst = v;
    }
  } else {
    // 32 frags: hL(2) x dt(4) x k32l(4); key order PERM(quad, j).
#pragma unroll
    for (int i = 0; i < 8; ++i) {
      const int fi   = i * 4 + w;
      const int hL   = fi >> 4, dt = (fi >> 2) & 3, k32l = fi & 3;
      const bf16_t* Trow = &u.T[hL * 64 + dt * 16 + l15][0];
      const int r0 = k32l * 32 + (quad >> 1) * 16 + (quad & 1) * 4;
      union { uint2 d2[2]; bf16x8 v; } vv;
      vv.d2[0] = *(const uint2*)(Trow + r0);       // keys r0..r0+3  -> j=0..3
      vv.d2[1] = *(const uint2*)(Trow + r0 + 8);   // keys r0+8..+11 -> j=4..7
      const int gr = m0 + k32l * 32;               // key base (same b for block)
      const int b = gr >> 11, n = gr & (NSEQ - 1);
      const int bh = b * HEADS + ((n0 - 512) >> 6) + hL;
      bf16_t* dst = Vf + (((size_t)(bh * 64 + (n >> 5)) * 4 + dt)) * 512 + lane * 8;
      *(bf16x8*)dst = vv.v;
    }
  }
}

// ---------------------------------------------------------------------------
// Flash attention, Q = K, fixed max m_i = ||k_i||^2, S^T trick.
// R17 = R9 VERBATIM + wave-phase STAGGER. Closed hypotheses: occupancy
// (R15: +76% waves -> +-0%), MFMA-side work removal (R16: moved row-sum to
// the saturated VALU pipe, -2.7us regression). R9's profile (MfmaUtil 33 +
// VALUBusy 53 = 86%) is the signature of co-SIMD waves running the same
// burst sequence IN PHASE: both hit the exp (VALU) phase together while the
// matrix pipe idles, and vice versa. A one-time s_sleep at loop entry
// (slots 0/128/256/384 cyc by wave id ^ block parity — co-resident blocks
// pair same-w waves on a SIMD) anti-phases them so one wave's exp fills the
// other's MFMA shadow. Zero work added; if the scheduler re-equalizes, the
// change is a clean null.
// ---------------------------------------------------------------------------
__global__ __launch_bounds__(256, 2) void flash_kernel(
    const bf16_t* __restrict__ Kf, const bf16_t* __restrict__ Vf,
    float* __restrict__ out)
{
  __shared__ struct {
    __align__(16) float Cb[2][4096];       // key-half-1 O partials
    __align__(16) float Lb[2][64][16];     // key-half-1 l partials
  } u;

  const int t    = threadIdx.x;
  const int w    = t >> 6;
  const int lane = t & 63;
  const int quad = lane >> 4;
  const int l15  = lane & 15;
  const int rh   = w & 1;              // row-half
  const int kh   = w >> 1;             // key-half

  const int bh = blockIdx.x;           // 0..31 (id%8 = bh%8 -> XCD locality)
  const int b  = bh >> 3, h = bh & 7;
  const int rowbase = blockIdx.y * 128 + rh * 64;
  const int qtile   = rowbase >> 4;    // 16-row tile base 0..124

  const bf16_t* __restrict__ Kb = Kf + (size_t)bh * 128 * 2 * 512;
  const bf16_t* __restrict__ Vb = Vf + (size_t)bh * 64 * 4 * 512;

  // Resident Q fragments (coalesced frag loads; B-operand of S^T).
  bf16x8 qf[4][2];
#pragma unroll
  for (int nt = 0; nt < 4; ++nt)
#pragma unroll
    for (int kk = 0; kk < 2; ++kk)
      qf[nt][kk] = *(const bf16x8*)(Kb + ((size_t)(qtile + nt) * 2 + kk) * 512 + lane * 8);

  // Fixed max m_i = ||k_i||^2; lane's q-row for tile nt is nt*16+l15.
  float mlog[4];
#pragma unroll
  for (int nt = 0; nt < 4; ++nt) {
    float ss = 0.f;
#pragma unroll
    for (int kk = 0; kk < 2; ++kk)
#pragma unroll
      for (int j = 0; j < 8; ++j) {
        const float qv = (float)qf[nt][kk][j];
        ss = fmaf(qv, qv, ss);
      }
    ss += __shfl_xor(ss, 16, 64);
    ss += __shfl_xor(ss, 32, 64);
    mlog[nt] = ss * LOG2E;
  }

  // R17: anti-phase co-SIMD waves (see header comment).
  {
    const int slot = (w + ((blockIdx.y & 1) << 1)) & 3;
    if (slot == 1)      __builtin_amdgcn_s_sleep(2);   // ~128 cyc
    else if (slot == 2) __builtin_amdgcn_s_sleep(4);   // ~256 cyc
    else if (slot == 3) __builtin_amdgcn_s_sleep(6);   // ~384 cyc
  }

  bf16x8 ones;
#pragma unroll
  for (int j = 0; j < 8; ++j) ones[j] = (bf16_t)1.0f;

  f32x4 acco[4][4] = {};   // [row-tile][d-tile]
  f32x4 accll[4]   = {};   // l partials via ones-MFMA (C-layout)

  // K frag loader: keys kt*64 + kh*32 .. +31 = 16-key tiles kt*4+kh*2+{0,1}
  auto load_k = [&](int kt, bf16x8 (&dst)[2][2]) {
    const int kb = kt * 4 + kh * 2;
#pragma unroll
    for (int jt = 0; jt < 2; ++jt)
#pragma unroll
      for (int kk = 0; kk < 2; ++kk)
        dst[jt][kk] =
            *(const bf16x8*)(Kb + ((size_t)(kb + jt) * 2 + kk) * 512 + lane * 8);
  };

  // One tile: uses kcur (resident), prefetches kt+1 into knxt.
  auto body = [&](int kt, bf16x8 (&kcur)[2][2], bf16x8 (&knxt)[2][2]) {
    // V frags for current tile (consumed after S-phase).
    bf16x8 vf[4];
    const int v32 = kt * 2 + kh;
#pragma unroll
    for (int dt = 0; dt < 4; ++dt)
      vf[dt] = *(const bf16x8*)(Vb + ((size_t)v32 * 4 + dt) * 512 + lane * 8);

    // S^T = K . Q^T.
    f32x4 st[2][4] = {};
    __builtin_amdgcn_s_setprio(1);
#pragma unroll
    for (int kk = 0; kk < 2; ++kk)
#pragma unroll
      for (int jt = 0; jt < 2; ++jt)
#pragma unroll
        for (int nt = 0; nt < 4; ++nt)
          st[jt][nt] = MFMA16(kcur[jt][kk], qf[nt][kk], st[jt][nt]);
    __builtin_amdgcn_s_setprio(0);

    // Prefetch next K tile (clamped on last iter).
    load_k(kt + 1 < NSEQ / 64 ? kt + 1 : kt, knxt);

    // P = exp2(S*log2e - m), packed to bf16 pairs and transposed C->A
    // in-register: two permlane32_swap per row-tile. Resulting lane key
    // order is PERM(quad, j), which Vf's store order matches.
    bf16x8 pf[4];
#pragma unroll
    for (int nt = 0; nt < 4; ++nt) {
      union { bf16_t h[2]; unsigned uu; } w00, w01, w10, w11;
      w00.h[0] = (bf16_t)__builtin_amdgcn_exp2f(fmaf(st[0][nt][0], LOG2E, -mlog[nt]));
      w00.h[1] = (bf16_t)__builtin_amdgcn_exp2f(fmaf(st[0][nt][1], LOG2E, -mlog[nt]));
      w01.h[0] = (bf16_t)__builtin_amdgcn_exp2f(fmaf(st[0][nt][2], LOG2E, -mlog[nt]));
      w01.h[1] = (bf16_t)__builtin_amdgcn_exp2f(fmaf(st[0][nt][3], LOG2E, -mlog[nt]));
      w10.h[0] = (bf16_t)__builtin_amdgcn_exp2f(fmaf(st[1][nt][0], LOG2E, -mlog[nt]));
      w10.h[1] = (bf16_t)__builtin_amdgcn_exp2f(fmaf(st[1][nt][1], LOG2E, -mlog[nt]));
      w11.h[0] = (bf16_t)__builtin_amdgcn_exp2f(fmaf(st[1][nt][2], LOG2E, -mlog[nt]));
      w11.h[1] = (bf16_t)__builtin_amdgcn_exp2f(fmaf(st[1][nt][3], LOG2E, -mlog[nt]));
      // swap row1(a)<->row0(b): a' = quads {a.q0, a.q1, b.q0, b.q1},
      //                         b' = quads {a.q2, a.q3, b.q2, b.q3}
      auto r0 = __builtin_amdgcn_permlane32_swap(w00.uu, w10.uu, false, false);
      auto r1 = __builtin_amdgcn_permlane32_swap(w01.uu, w11.uu, false, false);
      union { unsigned uw[4]; bf16x8 v; } pk;
      pk.uw[0] = r0[0]; pk.uw[1] = r1[0]; pk.uw[2] = r0[1]; pk.uw[3] = r1[1];
      pf[nt] = pk.v;
    }

    // O += P V, l += P . 1 (all in registers).
    __builtin_amdgcn_s_setprio(1);
#pragma unroll
    for (int rt = 0; rt < 4; ++rt) {
      accll[rt] = MFMA16(pf[rt], ones, accll[rt]);
#pragma unroll
      for (int dt = 0; dt < 4; ++dt)
        acco[rt][dt] = MFMA16(pf[rt], vf[dt], acco[rt][dt]);
    }
    __builtin_amdgcn_s_setprio(0);
  };

  bf16x8 kA[2][2], kB[2][2];
  load_k(0, kA);
  for (int kt = 0; kt < NSEQ / 64; kt += 2) {
    body(kt,     kA, kB);   // static buffer names -> no dynamic reg indexing
    body(kt + 1, kB, kA);
  }

  // Split-K combine: key-half-1 waves dump partials; key-half-0 waves add.
  __syncthreads();
  if (kh == 1) {
#pragma unroll
    for (int rt = 0; rt < 4; ++rt) {
#pragma unroll
      for (int dt = 0; dt < 4; ++dt)
        *(f32x4*)(&u.Cb[rh][((rt * 4 + dt) * 64 + lane) * 4]) = acco[rt][dt];
      *(f32x4*)(&u.Lb[rh][lane][rt * 4]) = accll[rt];
    }
  }
  __syncthreads();
  if (kh == 0) {
#pragma unroll
    for (int rt = 0; rt < 4; ++rt) {
#pragma unroll
      for (int dt = 0; dt < 4; ++dt)
        acco[rt][dt] += *(const f32x4*)(&u.Cb[rh][((rt * 4 + dt) * 64 + lane) * 4]);
      accll[rt] += *(const f32x4*)(&u.Lb[rh][lane][rt * 4]);
    }

    const float SCL = 0.044194173824159216f;  // 1/sqrt(512)
    // accll[rt][reg] = l of q-row rt*16+quad*4+reg — already acco-aligned.
#pragma unroll
    for (int rt = 0; rt < 4; ++rt)
#pragma unroll
      for (int reg = 0; reg < 4; ++reg) {
        const float f = SCL / accll[rt][reg];
        const int n = rowbase + rt * 16 + quad * 4 + reg;
#pragma unroll
        for (int dt = 0; dt < 4; ++dt)
          out[((size_t)(b * NSEQ + n)) * EMB + h * HD + dt * 16 + l15] =
              acco[rt][dt][reg] * f;
      }
  }
}

extern "C" void kernel_launch(void* const* d_in, const int* in_sizes, int n_in,
                              void* d_out, int out_size, void* d_ws, size_t ws_size,
                              hipStream_t stream) {
  const float* x  = (const float*)d_in[0];
  const float* Wk = (const float*)d_in[1];
  const float* bk = (const float*)d_in[2];
  const float* Wv = (const float*)d_in[3];
  const float* bv = (const float*)d_in[4];
  float* out = (float*)d_out;

  bf16_t* Kf = (bf16_t*)d_ws;                                   // 8 MB
  bf16_t* Vf = Kf + (size_t)BATCH * HEADS * NSEQ * HD;          // 8 MB

  dim3 pg(8192 / 128, 1024 / 128);
  proj_kernel<<<pg, 256, 0, stream>>>(x, Wk, bk, Wv, bv, Kf, Vf);

  dim3 fg(BATCH * HEADS, NSEQ / 128);
  flash_kernel<<<fg, 256, 0, stream>>>(Kf, Vf, out);
}